// Round 4
// baseline (1769.256 us; speedup 1.0000x reference)
//
#include <hip/hip_runtime.h>
#include <stdint.h>

#define B_SZ   4096
#define IN_SZ  1024
#define NE     8
#define NC     1000
#define HIDE   16384   // HID*E
#define OUTE   1024    // OUT per expert
#define GEPS   1e-6f
#define NSPLIT 4
#define KSPL   4096    // HIDE / NSPLIT
#define NT_MOE 64      // KSPL / 64
#define NT_H   16      // IN_SZ / 64

typedef __attribute__((ext_vector_type(8))) short short8;
typedef __attribute__((ext_vector_type(4))) float floatx4;

__device__ __forceinline__ unsigned short f2bf(float f) {
    unsigned u = __float_as_uint(f);
    u += 0x7fffu + ((u >> 16) & 1u);
    return (unsigned short)(u >> 16);
}
__device__ __forceinline__ float bf2f(unsigned short h) {
    return __uint_as_float(((unsigned)h) << 16);
}

__device__ __forceinline__ void async16(const void* g, void* l) {
    __builtin_amdgcn_global_load_lds(
        (const __attribute__((address_space(1))) void*)g,
        (__attribute__((address_space(3))) void*)l, 16, 0, 0);
}

// stage one 128x64 half-tile (16KB): 8 waves x 2 calls x 64 lanes x 16B
__device__ __forceinline__ void stage_half(const unsigned short* p0, const unsigned short* p1,
                                           char* smemc, int ldsoff, int w, int tt) {
    async16(p0 + (size_t)tt * 64, smemc + ldsoff + w * 1024);
    async16(p1 + (size_t)tt * 64, smemc + ldsoff + 8192 + w * 1024);
}

// ---------------- conversion fp32 -> bf16 ---------------------------------------
__global__ __launch_bounds__(256) void k_cvt(const float* __restrict__ src,
                                             unsigned short* __restrict__ dst, int n) {
    int i = (blockIdx.x * 256 + threadIdx.x) * 4;
    int stride = gridDim.x * 256 * 4;
    for (; i < n; i += stride) {
        float4 v = *(const float4*)(src + i);
        ushort4 o;
        o.x = f2bf(v.x); o.y = f2bf(v.y); o.z = f2bf(v.z); o.w = f2bf(v.w);
        *(ushort4*)(dst + i) = o;
    }
}

// ---------------- gating (fp32 exact) -------------------------------------------
__global__ __launch_bounds__(256) void k_gate(const float* __restrict__ x,
                                              const float* __restrict__ Wg,
                                              const float* __restrict__ bg,
                                              float* __restrict__ logits,
                                              float* __restrict__ Gx) {
    int wid = threadIdx.x >> 6, lane = threadIdx.x & 63;
    int b = blockIdx.x * 4 + wid;
    const float* xr = x + (size_t)b * IN_SZ;
    float xv[16];
#pragma unroll
    for (int t = 0; t < 16; ++t) xv[t] = xr[lane + 64 * t];
    float lg[NE];
#pragma unroll
    for (int e = 0; e < NE; ++e) {
        const float* wr = Wg + e * IN_SZ;
        float s = 0.f;
#pragma unroll
        for (int t = 0; t < 16; ++t) s += xv[t] * wr[lane + 64 * t];
#pragma unroll
        for (int m = 32; m >= 1; m >>= 1) s += __shfl_xor(s, m, 64);
        lg[e] = s + bg[e];
    }
    if (lane == 0) {
        float ss = 0.f;
#pragma unroll
        for (int e = 0; e < NE; ++e) { logits[b * NE + e] = lg[e]; ss += lg[e] * lg[e]; }
        Gx[b] = sqrtf(ss);
    }
}

__global__ __launch_bounds__(1024) void k_gsum(const float* __restrict__ Gx, float* __restrict__ gsum) {
    __shared__ float sm[1024];
    int t = threadIdx.x;
    sm[t] = Gx[t] + Gx[t + 1024] + Gx[t + 2048] + Gx[t + 3072];
    __syncthreads();
    for (int m = 512; m >= 1; m >>= 1) {
        if (t < m) sm[t] += sm[t + m];
        __syncthreads();
    }
    if (t == 0) gsum[0] = sm[0];
}

__global__ void k_zeroctrl(int* ctrl) {
    if (threadIdx.x < 24) ctrl[threadIdx.x] = 0;
}

__global__ __launch_bounds__(256) void k_topk(const float* __restrict__ logits,
                                              const float* __restrict__ Gx,
                                              const float* __restrict__ gsum,
                                              const float* __restrict__ gamma,
                                              const float* __restrict__ beta,
                                              int* __restrict__ tidx, float* __restrict__ tp,
                                              int* __restrict__ counts) {
    int b = blockIdx.x * 256 + threadIdx.x;
    float nx = Gx[b] / (gsum[0] * (1.0f / (float)B_SZ) + GEPS);
    float l[NE];
    float mx = -1e30f;
#pragma unroll
    for (int e = 0; e < NE; ++e) {
        l[e] = gamma[e] * (logits[b * NE + e] * nx) + beta[e];
        mx = fmaxf(mx, l[e]);
    }
    float se = 0.f;
#pragma unroll
    for (int e = 0; e < NE; ++e) { l[e] = expf(l[e] - mx); se += l[e]; }
    float inv = 1.f / se;
    int i0 = 0; float p0 = l[0];
#pragma unroll
    for (int e = 1; e < NE; ++e) if (l[e] > p0) { p0 = l[e]; i0 = e; }
    int i1 = -1; float p1 = -1.f;
#pragma unroll
    for (int e = 0; e < NE; ++e) if (e != i0 && l[e] > p1) { p1 = l[e]; i1 = e; }
    tidx[b * 2 + 0] = i0; tidx[b * 2 + 1] = i1;
    tp[b * 2 + 0] = p0 * inv; tp[b * 2 + 1] = p1 * inv;
    atomicAdd(&counts[i0], 1);
    atomicAdd(&counts[i1], 1);
}

__global__ void k_offsets(const int* __restrict__ counts, int* __restrict__ offs) {
    if (threadIdx.x == 0) {
        int a = 0;
        for (int e = 0; e < NE; ++e) { offs[e] = a; a += counts[e]; }
    }
}

__global__ __launch_bounds__(256) void k_fill(const int* __restrict__ tidx, const float* __restrict__ tp,
                                              const int* __restrict__ offs, int* __restrict__ cursors,
                                              int* __restrict__ rowsw, int* __restrict__ slotof) {
    int b = blockIdx.x * 256 + threadIdx.x;
#pragma unroll
    for (int k = 0; k < 2; ++k) {
        int e = tidx[b * 2 + k];
        int pos = atomicAdd(&cursors[e], 1);
        int at = offs[e] + pos;
        rowsw[at] = b * 2 + k;
        slotof[b * 2 + k] = at;
    }
}

// =====================  256x256 / BK64 8-phase MFMA core  =======================
// LDS per buffer (64KB): A half0(16K) | A half1 | B half0 | B half1 ; 2 buffers.
// Swizzle: LDS(row,slot) holds global chunk slot^(row&7)  (16B chunks).
//
// Phase shape (template-faithful): reads+stage BEFORE the pre-MFMA barrier so
// ds_read latency hides under the barrier wait; lgkmcnt(0)+sched_barrier(0)
// after the barrier; setprio around the MFMA cluster; post-MFMA barrier.
// Stage plan per tile t: P1: B0(t+1); P2: B1(t+1); P3: A0(t+2)+A1(t+2), then
// vmcnt(4) (12 outstanding -> retires exactly tile t+1's 4 halves). P3's
// post-barrier postdates every wave's vmcnt => P0(t+1) reads are race-free.
// Tail: t+2>=NT -> vmcnt(0) (drains B halves of the last tile; round-3 fix).

#define MFMA_PAIR(JA, JB) \
  __builtin_amdgcn_s_setprio(1); \
  _Pragma("unroll") \
  for (int i_ = 0; i_ < 8; ++i_) { \
    acc[i_][JA] = __builtin_amdgcn_mfma_f32_16x16x32_bf16(av[i_], bva, acc[i_][JA], 0, 0, 0); \
    acc[i_][JB] = __builtin_amdgcn_mfma_f32_16x16x32_bf16(av[i_], bvb, acc[i_][JB], 0, 0, 0); \
  } \
  __builtin_amdgcn_s_setprio(0);

#define PRE_MFMA  __builtin_amdgcn_s_barrier(); \
                  asm volatile("s_waitcnt lgkmcnt(0)" ::: "memory"); \
                  __builtin_amdgcn_sched_barrier(0);
#define POST_MFMA __builtin_amdgcn_s_barrier();

#define TILE_BODY(T_, BUF_, NTT_) do { \
  const int tq1_ = (T_) + 1, tq2_ = (T_) + 2; \
  const short* Ab_ = smem + (BUF_) * 32768 + wm * 8192; \
  const short* Bb_ = smem + (BUF_) * 32768 + 16384 + (wn >> 1) * 8192; \
  short8 av[8], bva, bvb; \
  /* P0 */ \
  _Pragma("unroll") \
  for (int i_ = 0; i_ < 8; ++i_) av[i_] = *(const short8*)(Ab_ + aoff[i_]); \
  bva = *(const short8*)(Bb_ + boff[0]); \
  bvb = *(const short8*)(Bb_ + boff[1]); \
  PRE_MFMA MFMA_PAIR(0, 1) POST_MFMA \
  /* P1 */ \
  bva = *(const short8*)(Bb_ + boff[2]); \
  bvb = *(const short8*)(Bb_ + boff[3]); \
  if (tq1_ < (NTT_)) stage_half(pB[0][0], pB[0][1], smemc, ((tq1_ & 1) * 65536) + 32768, w, tq1_); \
  PRE_MFMA MFMA_PAIR(2, 3) POST_MFMA \
  /* P2 */ \
  _Pragma("unroll") \
  for (int i_ = 0; i_ < 8; ++i_) av[i_] = *(const short8*)(Ab_ + (aoff[i_] ^ 32)); \
  bva = *(const short8*)(Bb_ + (boff[0] ^ 32)); \
  bvb = *(const short8*)(Bb_ + (boff[1] ^ 32)); \
  if (tq1_ < (NTT_)) stage_half(pB[1][0], pB[1][1], smemc, ((tq1_ & 1) * 65536) + 49152, w, tq1_); \
  PRE_MFMA MFMA_PAIR(0, 1) POST_MFMA \
  /* P3 */ \
  bva = *(const short8*)(Bb_ + (boff[2] ^ 32)); \
  bvb = *(const short8*)(Bb_ + (boff[3] ^ 32)); \
  if (tq2_ < (NTT_)) { \
    stage_half(pA[0][0], pA[0][1], smemc, ((tq2_ & 1) * 65536) + 0,     w, tq2_); \
    stage_half(pA[1][0], pA[1][1], smemc, ((tq2_ & 1) * 65536) + 16384, w, tq2_); \
    asm volatile("s_waitcnt vmcnt(4)" ::: "memory"); \
  } else { \
    asm volatile("s_waitcnt vmcnt(0)" ::: "memory"); \
  } \
  PRE_MFMA MFMA_PAIR(2, 3) POST_MFMA \
} while (0)

// Prologue: all 4 halves of tile0 + A halves of tile1; vmcnt(4) retains only
// A(1) in flight -> tile0 fully landed after the barrier.
#define CORE_PROLOGUE(NTT_) \
  stage_half(pA[0][0], pA[0][1], smemc, 0,     w, 0); \
  stage_half(pA[1][0], pA[1][1], smemc, 16384, w, 0); \
  stage_half(pB[0][0], pB[0][1], smemc, 32768, w, 0); \
  stage_half(pB[1][0], pB[1][1], smemc, 49152, w, 0); \
  if ((NTT_) > 1) { \
    stage_half(pA[0][0], pA[0][1], smemc, 65536 + 0,     w, 1); \
    stage_half(pA[1][0], pA[1][1], smemc, 65536 + 16384, w, 1); \
    asm volatile("s_waitcnt vmcnt(4)" ::: "memory"); \
  } else { \
    asm volatile("s_waitcnt vmcnt(0)" ::: "memory"); \
  } \
  __builtin_amdgcn_s_barrier();

// GEMM1: h = relu(x @ W1^T + b1)  [4096,1024] x [16384,1024]^T -> bf16 [4096,16384]
__global__ __launch_bounds__(512, 1) void k_h8(const unsigned short* __restrict__ xb,
                                               const unsigned short* __restrict__ w1b,
                                               const float* __restrict__ b1,
                                               unsigned short* __restrict__ hout) {
    extern __shared__ short smem[];
    char* smemc = (char*)smem;
    const int tid = threadIdx.x, lane = tid & 63, w = tid >> 6;
    const int wm = w >> 2, wn = w & 3;
    // bijective XCD swizzle (grid 1024, %8==0): consecutive wg share nt (B-panel)
    const int q = gridDim.x >> 3;
    const int wg = (blockIdx.x & 7) * q + (blockIdx.x >> 3);
    const int mt = wg & 15, nt = wg >> 4;
    const int m0 = mt * 256, n0 = nt * 256;
    const int ccs = ((lane & 7) ^ (lane >> 3)) * 8;   // pre-swizzled source chunk
    const unsigned short* pA[2][2];
    const unsigned short* pB[2][2];
#pragma unroll
    for (int h = 0; h < 2; ++h)
#pragma unroll
        for (int c = 0; c < 2; ++c) {
            pA[h][c] = xb  + (size_t)(m0 + h * 128 + c * 64 + w * 8 + (lane >> 3)) * IN_SZ + ccs;
            pB[h][c] = w1b + (size_t)(n0 + h * 128 + c * 64 + w * 8 + (lane >> 3)) * IN_SZ + ccs;
        }
    int aoff[8], boff[4];
#pragma unroll
    for (int i = 0; i < 8; ++i)
        aoff[i] = (i * 16 + (lane & 15)) * 64 + (((lane >> 4) ^ (lane & 7)) * 8);
#pragma unroll
    for (int j = 0; j < 4; ++j)
        boff[j] = ((wn & 1) * 64 + j * 16 + (lane & 15)) * 64 + (((lane >> 4) ^ (lane & 7)) * 8);
    floatx4 acc[8][4] = {};
    CORE_PROLOGUE(NT_H)
    for (int t = 0; t < NT_H; t += 2) { TILE_BODY(t, 0, NT_H); TILE_BODY(t + 1, 1, NT_H); }
#pragma unroll
    for (int i = 0; i < 8; ++i)
#pragma unroll
        for (int j = 0; j < 4; ++j)
#pragma unroll
            for (int r = 0; r < 4; ++r) {
                int row = m0 + wm * 128 + i * 16 + (lane >> 4) * 4 + r;
                int col = n0 + wn * 64 + j * 16 + (lane & 15);
                float v = acc[i][j][r] + b1[col];
                hout[(size_t)row * HIDE + col] = f2bf(fmaxf(v, 0.f));
            }
}

// GEMM2 grouped, split-K=4: gathered h rows x W2 expert slice -> bf16 partials
__global__ __launch_bounds__(512, 1) void k_moe8(const unsigned short* __restrict__ h,
                                                 const unsigned short* __restrict__ w2b,
                                                 const int* __restrict__ counts,
                                                 const int* __restrict__ offs,
                                                 const int* __restrict__ rowsw,
                                                 unsigned short* __restrict__ parts) {
    extern __shared__ short smem[];
    char* smemc = (char*)smem;
    // swizzle (grid 2048): same-XCD neighbors share (e,nt,sp) B-panel in L2
    const int q = gridDim.x >> 3;
    const int wg = (blockIdx.x & 7) * q + (blockIdx.x >> 3);
    const int mt = wg & 15, sp = (wg >> 4) & 3, nt = (wg >> 6) & 3, e = wg >> 8;
    const int gn = counts[e];
    if (mt * 256 >= gn) return;
    const int gbase = offs[e];
    const int tid = threadIdx.x, lane = tid & 63, w = tid >> 6;
    const int wm = w >> 2, wn = w & 3;
    const int ccs = ((lane & 7) ^ (lane >> 3)) * 8;
    const unsigned short* pA[2][2];
    const unsigned short* pB[2][2];
#pragma unroll
    for (int hh = 0; hh < 2; ++hh)
#pragma unroll
        for (int c = 0; c < 2; ++c) {
            int lr = mt * 256 + hh * 128 + c * 64 + w * 8 + (lane >> 3);
            if (lr > gn - 1) lr = gn - 1;
            int grow = rowsw[gbase + lr] >> 1;
            pA[hh][c] = h + (size_t)grow * HIDE + sp * KSPL + ccs;
            int brow = e * OUTE + nt * 256 + hh * 128 + c * 64 + w * 8 + (lane >> 3);
            pB[hh][c] = w2b + (size_t)brow * HIDE + sp * KSPL + ccs;
        }
    int aoff[8], boff[4];
#pragma unroll
    for (int i = 0; i < 8; ++i)
        aoff[i] = (i * 16 + (lane & 15)) * 64 + (((lane >> 4) ^ (lane & 7)) * 8);
#pragma unroll
    for (int j = 0; j < 4; ++j)
        boff[j] = ((wn & 1) * 64 + j * 16 + (lane & 15)) * 64 + (((lane >> 4) ^ (lane & 7)) * 8);
    floatx4 acc[8][4] = {};
    CORE_PROLOGUE(NT_MOE)
    for (int t = 0; t < NT_MOE; t += 2) { TILE_BODY(t, 0, NT_MOE); TILE_BODY(t + 1, 1, NT_MOE); }
    unsigned short* pbase = parts + (size_t)sp * B_SZ * 2 * OUTE;
#pragma unroll
    for (int i = 0; i < 8; ++i)
#pragma unroll
        for (int j = 0; j < 4; ++j)
#pragma unroll
            for (int r = 0; r < 4; ++r) {
                int lr = mt * 256 + wm * 128 + i * 16 + (lane >> 4) * 4 + r;
                if (lr < gn) {
                    int at = gbase + lr;
                    int col = nt * 256 + wn * 64 + j * 16 + (lane & 15);
                    pbase[(size_t)at * OUTE + col] = f2bf(acc[i][j][r]);
                }
            }
}

// reduce: ymix[b] = sum_k tp[b,k] * (sum_sp parts[sp][slot(b,k)] + b2[e_k])
__global__ __launch_bounds__(256) void k_reduce(const unsigned short* __restrict__ parts,
                                                const int* __restrict__ slotof,
                                                const int* __restrict__ tidx,
                                                const float* __restrict__ tp,
                                                const float* __restrict__ b2,
                                                unsigned short* __restrict__ ymix) {
    int i = blockIdx.x * 256 + threadIdx.x;   // B_SZ * 256 threads, 4 cols each
    int b = i >> 8, col = (i & 255) * 4;
    int at0 = slotof[b * 2], at1 = slotof[b * 2 + 1];
    int e0 = tidx[b * 2], e1 = tidx[b * 2 + 1];
    float q0 = tp[b * 2], q1 = tp[b * 2 + 1];
    float y0[4] = {0.f, 0.f, 0.f, 0.f}, y1[4] = {0.f, 0.f, 0.f, 0.f};
#pragma unroll
    for (int sp = 0; sp < NSPLIT; ++sp) {
        ushort4 u0 = *(const ushort4*)(parts + ((size_t)sp * B_SZ * 2 + at0) * OUTE + col);
        ushort4 u1 = *(const ushort4*)(parts + ((size_t)sp * B_SZ * 2 + at1) * OUTE + col);
        y0[0] += bf2f(u0.x); y0[1] += bf2f(u0.y); y0[2] += bf2f(u0.z); y0[3] += bf2f(u0.w);
        y1[0] += bf2f(u1.x); y1[1] += bf2f(u1.y); y1[2] += bf2f(u1.z); y1[3] += bf2f(u1.w);
    }
    float4 bb0 = *(const float4*)(b2 + (size_t)e0 * OUTE + col);
    float4 bb1 = *(const float4*)(b2 + (size_t)e1 * OUTE + col);
    ushort4 o;
    o.x = f2bf(q0 * (y0[0] + bb0.x) + q1 * (y1[0] + bb1.x));
    o.y = f2bf(q0 * (y0[1] + bb0.y) + q1 * (y1[1] + bb1.y));
    o.z = f2bf(q0 * (y0[2] + bb0.z) + q1 * (y1[2] + bb1.z));
    o.w = f2bf(q0 * (y0[3] + bb0.w) + q1 * (y1[3] + bb1.w));
    *(ushort4*)(ymix + (size_t)b * OUTE + col) = o;
}

// ---------------- m97-style 128x128 core (small final GEMM) --------------------
__device__ __forceinline__ void gemm_core(const unsigned short* sa0, const unsigned short* sa1,
                                          const unsigned short* sb0, const unsigned short* sb1,
                                          short* sA, short* sB, int nkt, int wid, int lane,
                                          floatx4 acc[4][4]) {
    short* ldsA0 = sA + (wid * 2 + 0) * 512;
    short* ldsA1 = sA + (wid * 2 + 1) * 512;
    short* ldsB0 = sB + (wid * 2 + 0) * 512;
    short* ldsB1 = sB + (wid * 2 + 1) * 512;
    const int wm = wid >> 1, wn = wid & 1;
    int aoff[4], boff[4];
#pragma unroll
    for (int i = 0; i < 4; ++i) {
        aoff[i] = (wm * 64 + i * 16 + (lane & 15)) * 32 + (lane >> 4) * 8;
        boff[i] = (wn * 64 + i * 16 + (lane & 15)) * 32 + (lane >> 4) * 8;
    }
    for (int kt = 0; kt < nkt; ++kt) {
        __syncthreads();
        async16(sa0, ldsA0);
        async16(sa1, ldsA1);
        async16(sb0, ldsB0);
        async16(sb1, ldsB1);
        sa0 += 32; sa1 += 32; sb0 += 32; sb1 += 32;
        __syncthreads();
        short8 av[4], bv[4];
#pragma unroll
        for (int i = 0; i < 4; ++i) av[i] = *(const short8*)(sA + aoff[i]);
#pragma unroll
        for (int j = 0; j < 4; ++j) bv[j] = *(const short8*)(sB + boff[j]);
#pragma unroll
        for (int i = 0; i < 4; ++i)
#pragma unroll
            for (int j = 0; j < 4; ++j)
                acc[i][j] = __builtin_amdgcn_mfma_f32_16x16x32_bf16(av[i], bv[j], acc[i][j], 0, 0, 0);
    }
}

// GEMM3: out = ymix @ Wc^T + bc
__global__ __launch_bounds__(256) void k_gemm_out(const unsigned short* __restrict__ ymix,
                                                  const unsigned short* __restrict__ wcb,
                                                  const float* __restrict__ bc,
                                                  float* __restrict__ out) {
    const int mt = blockIdx.x >> 3, nt = blockIdx.x & 7;
    const int m0 = mt * 128, n0 = nt * 128;
    __shared__ __align__(16) short sA[128 * 32];
    __shared__ __align__(16) short sB[128 * 32];
    const int lane = threadIdx.x & 63, wid = threadIdx.x >> 6;
    const int t0row = (wid * 2 + 0) * 16 + (lane >> 2);
    const int t1row = (wid * 2 + 1) * 16 + (lane >> 2);
    const int kb = (lane & 3) * 8;
    int br0 = n0 + t0row; if (br0 > NC - 1) br0 = NC - 1;
    int br1 = n0 + t1row; if (br1 > NC - 1) br1 = NC - 1;
    const unsigned short* sa0 = ymix + (size_t)(m0 + t0row) * IN_SZ + kb;
    const unsigned short* sa1 = ymix + (size_t)(m0 + t1row) * IN_SZ + kb;
    const unsigned short* sb0 = wcb + (size_t)br0 * IN_SZ + kb;
    const unsigned short* sb1 = wcb + (size_t)br1 * IN_SZ + kb;
    floatx4 acc[4][4] = {};
    gemm_core(sa0, sa1, sb0, sb1, sA, sB, IN_SZ / 32, wid, lane, acc);
    const int wm = wid >> 1, wn = wid & 1;
#pragma unroll
    for (int i = 0; i < 4; ++i)
#pragma unroll
        for (int j = 0; j < 4; ++j)
#pragma unroll
            for (int r = 0; r < 4; ++r) {
                int row = m0 + wm * 64 + i * 16 + (lane >> 4) * 4 + r;
                int col = n0 + wn * 64 + j * 16 + (lane & 15);
                if (col < NC)
                    out[(size_t)row * NC + col] = acc[i][j][r] + bc[col];
            }
}

extern "C" void kernel_launch(void* const* d_in, const int* in_sizes, int n_in,
                              void* d_out, int out_size, void* d_ws, size_t ws_size,
                              hipStream_t stream) {
    const float* x     = (const float*)d_in[0];
    const float* Wg    = (const float*)d_in[1];
    const float* bg    = (const float*)d_in[2];
    const float* gamma = (const float*)d_in[3];
    const float* beta  = (const float*)d_in[4];
    const float* W1    = (const float*)d_in[5];
    const float* b1    = (const float*)d_in[6];
    const float* W2    = (const float*)d_in[7];
    const float* b2    = (const float*)d_in[8];
    const float* Wc    = (const float*)d_in[9];
    const float* bc    = (const float*)d_in[10];
    float* out = (float*)d_out;

    char* ws = (char*)d_ws;
    size_t o = 0;
    auto carve = [&](size_t bytes) { char* p = ws + o; o += (bytes + 255) & ~(size_t)255; return p; };
    unsigned short* xb    = (unsigned short*)carve((size_t)B_SZ * IN_SZ * 2);
    unsigned short* w1b   = (unsigned short*)carve((size_t)HIDE * IN_SZ * 2);
    unsigned short* w2b   = (unsigned short*)carve((size_t)NE * OUTE * HIDE * 2);
    unsigned short* wcb   = (unsigned short*)carve((size_t)NC * IN_SZ * 2);
    unsigned short* h     = (unsigned short*)carve((size_t)B_SZ * HIDE * 2);
    unsigned short* parts = (unsigned short*)carve((size_t)NSPLIT * B_SZ * 2 * OUTE * 2);
    unsigned short* ymix  = (unsigned short*)carve((size_t)B_SZ * OUTE * 2);
    float* logits = (float*)carve((size_t)B_SZ * NE * 4);
    float* Gx     = (float*)carve((size_t)B_SZ * 4);
    int*   tidx   = (int*)carve((size_t)B_SZ * 2 * 4);
    float* tp     = (float*)carve((size_t)B_SZ * 2 * 4);
    int*   rowsw  = (int*)carve((size_t)B_SZ * 2 * 4);
    int*   slotof = (int*)carve((size_t)B_SZ * 2 * 4);
    int*   ctrl   = (int*)carve(256);
    int* counts  = ctrl;
    int* cursors = ctrl + 8;
    int* offs    = ctrl + 16;
    float* gsum  = (float*)(ctrl + 24);

    // allow 128KB dynamic LDS for the 8-phase kernels (idempotent, not captured)
    hipFuncSetAttribute((const void*)k_h8,   hipFuncAttributeMaxDynamicSharedMemorySize, 131072);
    hipFuncSetAttribute((const void*)k_moe8, hipFuncAttributeMaxDynamicSharedMemorySize, 131072);

    k_cvt<<<2048, 256, 0, stream>>>(x,  xb,  B_SZ * IN_SZ);
    k_cvt<<<2048, 256, 0, stream>>>(W1, w1b, HIDE * IN_SZ);
    k_cvt<<<2048, 256, 0, stream>>>(W2, w2b, NE * OUTE * HIDE);
    k_cvt<<<2048, 256, 0, stream>>>(Wc, wcb, NC * IN_SZ);

    k_gate<<<B_SZ / 4, 256, 0, stream>>>(x, Wg, bg, logits, Gx);
    k_gsum<<<1, 1024, 0, stream>>>(Gx, gsum);
    k_zeroctrl<<<1, 64, 0, stream>>>(ctrl);
    k_topk<<<B_SZ / 256, 256, 0, stream>>>(logits, Gx, gsum, gamma, beta, tidx, tp, counts);
    k_offsets<<<1, 64, 0, stream>>>(counts, offs);
    k_fill<<<B_SZ / 256, 256, 0, stream>>>(tidx, tp, offs, cursors, rowsw, slotof);

    k_h8<<<(B_SZ / 256) * (HIDE / 256), 512, 131072, stream>>>(xb, w1b, b1, h);
    k_moe8<<<NE * 16 * 4 * NSPLIT, 512, 131072, stream>>>(h, w2b, counts, offs, rowsw, parts);
    k_reduce<<<B_SZ, 256, 0, stream>>>(parts, slotof, tidx, tp, b2, ymix);
    k_gemm_out<<<(B_SZ / 128) * 8, 256, 0, stream>>>(ymix, wcb, bc, out);
}

// Round 5
// 1063.309 us; speedup vs baseline: 1.6639x; 1.6639x over previous
//
#include <hip/hip_runtime.h>
#include <stdint.h>

#define B_SZ   4096
#define IN_SZ  1024
#define NE     8
#define NC     1000
#define HIDE   16384   // HID*E
#define OUTE   1024    // OUT per expert
#define GEPS   1e-6f
#define NSPLIT 2
#define KSPL   8192    // HIDE / NSPLIT

typedef __attribute__((ext_vector_type(8))) short short8;
typedef __attribute__((ext_vector_type(4))) float floatx4;

__device__ __forceinline__ unsigned short f2bf(float f) {
    unsigned u = __float_as_uint(f);
    u += 0x7fffu + ((u >> 16) & 1u);
    return (unsigned short)(u >> 16);
}
__device__ __forceinline__ float bf2f(unsigned short h) {
    return __uint_as_float(((unsigned)h) << 16);
}

__device__ __forceinline__ void async16(const void* g, void* l) {
    __builtin_amdgcn_global_load_lds(
        (const __attribute__((address_space(1))) void*)g,
        (__attribute__((address_space(3))) void*)l, 16, 0, 0);
}

// ---------------- conversion fp32 -> bf16 ---------------------------------------
__global__ __launch_bounds__(256) void k_cvt(const float* __restrict__ src,
                                             unsigned short* __restrict__ dst, int n) {
    int i = (blockIdx.x * 256 + threadIdx.x) * 4;
    int stride = gridDim.x * 256 * 4;
    for (; i < n; i += stride) {
        float4 v = *(const float4*)(src + i);
        ushort4 o;
        o.x = f2bf(v.x); o.y = f2bf(v.y); o.z = f2bf(v.z); o.w = f2bf(v.w);
        *(ushort4*)(dst + i) = o;
    }
}

// ---------------- gating (fp32 exact) -------------------------------------------
__global__ __launch_bounds__(256) void k_gate(const float* __restrict__ x,
                                              const float* __restrict__ Wg,
                                              const float* __restrict__ bg,
                                              float* __restrict__ logits,
                                              float* __restrict__ Gx) {
    int wid = threadIdx.x >> 6, lane = threadIdx.x & 63;
    int b = blockIdx.x * 4 + wid;
    const float* xr = x + (size_t)b * IN_SZ;
    float xv[16];
#pragma unroll
    for (int t = 0; t < 16; ++t) xv[t] = xr[lane + 64 * t];
    float lg[NE];
#pragma unroll
    for (int e = 0; e < NE; ++e) {
        const float* wr = Wg + e * IN_SZ;
        float s = 0.f;
#pragma unroll
        for (int t = 0; t < 16; ++t) s += xv[t] * wr[lane + 64 * t];
#pragma unroll
        for (int m = 32; m >= 1; m >>= 1) s += __shfl_xor(s, m, 64);
        lg[e] = s + bg[e];
    }
    if (lane == 0) {
        float ss = 0.f;
#pragma unroll
        for (int e = 0; e < NE; ++e) { logits[b * NE + e] = lg[e]; ss += lg[e] * lg[e]; }
        Gx[b] = sqrtf(ss);
    }
}

__global__ __launch_bounds__(1024) void k_gsum(const float* __restrict__ Gx, float* __restrict__ gsum) {
    __shared__ float sm[1024];
    int t = threadIdx.x;
    sm[t] = Gx[t] + Gx[t + 1024] + Gx[t + 2048] + Gx[t + 3072];
    __syncthreads();
    for (int m = 512; m >= 1; m >>= 1) {
        if (t < m) sm[t] += sm[t + m];
        __syncthreads();
    }
    if (t == 0) gsum[0] = sm[0];
}

__global__ void k_zeroctrl(int* ctrl) {
    if (threadIdx.x < 24) ctrl[threadIdx.x] = 0;
}

__global__ __launch_bounds__(256) void k_topk(const float* __restrict__ logits,
                                              const float* __restrict__ Gx,
                                              const float* __restrict__ gsum,
                                              const float* __restrict__ gamma,
                                              const float* __restrict__ beta,
                                              int* __restrict__ tidx, float* __restrict__ tp,
                                              int* __restrict__ counts) {
    int b = blockIdx.x * 256 + threadIdx.x;
    float nx = Gx[b] / (gsum[0] * (1.0f / (float)B_SZ) + GEPS);
    float l[NE];
    float mx = -1e30f;
#pragma unroll
    for (int e = 0; e < NE; ++e) {
        l[e] = gamma[e] * (logits[b * NE + e] * nx) + beta[e];
        mx = fmaxf(mx, l[e]);
    }
    float se = 0.f;
#pragma unroll
    for (int e = 0; e < NE; ++e) { l[e] = expf(l[e] - mx); se += l[e]; }
    float inv = 1.f / se;
    int i0 = 0; float p0 = l[0];
#pragma unroll
    for (int e = 1; e < NE; ++e) if (l[e] > p0) { p0 = l[e]; i0 = e; }
    int i1 = -1; float p1 = -1.f;
#pragma unroll
    for (int e = 0; e < NE; ++e) if (e != i0 && l[e] > p1) { p1 = l[e]; i1 = e; }
    tidx[b * 2 + 0] = i0; tidx[b * 2 + 1] = i1;
    tp[b * 2 + 0] = p0 * inv; tp[b * 2 + 1] = p1 * inv;
    atomicAdd(&counts[i0], 1);
    atomicAdd(&counts[i1], 1);
}

__global__ void k_offsets(const int* __restrict__ counts, int* __restrict__ offs) {
    if (threadIdx.x == 0) {
        int a = 0;
        for (int e = 0; e < NE; ++e) { offs[e] = a; a += counts[e]; }
    }
}

__global__ __launch_bounds__(256) void k_fill(const int* __restrict__ tidx, const float* __restrict__ tp,
                                              const int* __restrict__ offs, int* __restrict__ cursors,
                                              int* __restrict__ rowsw, int* __restrict__ slotof) {
    int b = blockIdx.x * 256 + threadIdx.x;
#pragma unroll
    for (int k = 0; k < 2; ++k) {
        int e = tidx[b * 2 + k];
        int pos = atomicAdd(&cursors[e], 1);
        int at = offs[e] + pos;
        rowsw[at] = b * 2 + k;
        slotof[b * 2 + k] = at;
    }
}

// ============ 128x128 / BK=64 core, conflict-free XOR-swizzled LDS ==============
// LDS tile: 128 rows x 64 bf16 (128B rows, 8 x 16B slots). LDS[r][s] holds
// global chunk s^(r&7) (both-sides swizzle: pre-swizzled global_load_lds source
// + swizzled ds_read offset). 16 lanes reading one column of 16 rows hit banks
// ((k^(r&7))*4)%32 -> 8 slot-banks x 2 rows = 2-way (free, m136).
// Simple 2-barrier loop (proven round-1 structure), 4 waves, acc 4x4.

__device__ __forceinline__ void core64(
    const unsigned short* pa0, const unsigned short* pa1,
    const unsigned short* pa2, const unsigned short* pa3,
    const unsigned short* pb0, const unsigned short* pb1,
    const unsigned short* pb2, const unsigned short* pb3,
    short* sA, short* sB, int nkt, int wm, int wn, int tid, int lane,
    floatx4 acc[4][4])
{
    char* sAc = (char*)sA;
    char* sBc = (char*)sB;
    const int sl = ((lane >> 4) ^ (lane & 7)) * 8;   // swizzled slot for khalf0
    int aoff[4], boff[4];
#pragma unroll
    for (int i = 0; i < 4; ++i) {
        aoff[i] = (wm * 64 + i * 16 + (lane & 15)) * 64 + sl;
        boff[i] = (wn * 64 + i * 16 + (lane & 15)) * 64 + sl;
    }
    for (int kt = 0; kt < nkt; ++kt) {
        __syncthreads();                       // prev reads done before overwrite
        async16(pa0, sAc + tid * 16);
        async16(pa1, sAc + 4096 + tid * 16);
        async16(pa2, sAc + 8192 + tid * 16);
        async16(pa3, sAc + 12288 + tid * 16);
        async16(pb0, sBc + tid * 16);
        async16(pb1, sBc + 4096 + tid * 16);
        async16(pb2, sBc + 8192 + tid * 16);
        async16(pb3, sBc + 12288 + tid * 16);
        pa0 += 64; pa1 += 64; pa2 += 64; pa3 += 64;
        pb0 += 64; pb1 += 64; pb2 += 64; pb3 += 64;
        __syncthreads();                       // drains vmcnt (compiler semantics)
        short8 a0[4], a1[4], b0[4], b1[4];
#pragma unroll
        for (int i = 0; i < 4; ++i) {
            a0[i] = *(const short8*)(sA + aoff[i]);
            a1[i] = *(const short8*)(sA + (aoff[i] ^ 32));   // khalf1: slot^4
            b0[i] = *(const short8*)(sB + boff[i]);
            b1[i] = *(const short8*)(sB + (boff[i] ^ 32));
        }
#pragma unroll
        for (int i = 0; i < 4; ++i)
#pragma unroll
            for (int j = 0; j < 4; ++j) {
                acc[i][j] = __builtin_amdgcn_mfma_f32_16x16x32_bf16(a0[i], b0[j], acc[i][j], 0, 0, 0);
                acc[i][j] = __builtin_amdgcn_mfma_f32_16x16x32_bf16(a1[i], b1[j], acc[i][j], 0, 0, 0);
            }
    }
}

// GEMM1: h = relu(x @ W1^T + b1)  [4096,1024] x [16384,1024]^T -> bf16 [4096,16384]
__global__ __launch_bounds__(256) void k_h8(const unsigned short* __restrict__ xb,
                                            const unsigned short* __restrict__ w1b,
                                            const float* __restrict__ b1,
                                            unsigned short* __restrict__ hout) {
    __shared__ __align__(16) short sA[128 * 64];
    __shared__ __align__(16) short sB[128 * 64];
    const int tid = threadIdx.x, lane = tid & 63, wid = tid >> 6;
    const int wm = wid >> 1, wn = wid & 1;
    // bijective XCD swizzle (grid 4096): same-XCD neighbors share nt (B-panel)
    const int wg = (blockIdx.x & 7) * (gridDim.x >> 3) + (blockIdx.x >> 3);
    const int mt = wg & 31, nt = wg >> 5;
    const int m0 = mt * 128, n0 = nt * 128;
    const int srow = tid >> 3;                         // 0..31 (staged row in call)
    const int cswz = ((tid & 7) ^ (srow & 7)) * 8;     // pre-swizzled source chunk
    const unsigned short* pa[4];
    const unsigned short* pb[4];
#pragma unroll
    for (int c = 0; c < 4; ++c) {
        pa[c] = xb  + (size_t)(m0 + 32 * c + srow) * IN_SZ + cswz;
        pb[c] = w1b + (size_t)(n0 + 32 * c + srow) * IN_SZ + cswz;
    }
    floatx4 acc[4][4] = {};
    core64(pa[0], pa[1], pa[2], pa[3], pb[0], pb[1], pb[2], pb[3],
           sA, sB, IN_SZ / 64, wm, wn, tid, lane, acc);
#pragma unroll
    for (int i = 0; i < 4; ++i)
#pragma unroll
        for (int j = 0; j < 4; ++j)
#pragma unroll
            for (int r = 0; r < 4; ++r) {
                int row = m0 + wm * 64 + i * 16 + (lane >> 4) * 4 + r;
                int col = n0 + wn * 64 + j * 16 + (lane & 15);
                float v = acc[i][j][r] + b1[col];
                hout[(size_t)row * HIDE + col] = f2bf(fmaxf(v, 0.f));
            }
}

// GEMM2 grouped, split-K=2: gathered h rows x W2 expert slice -> bf16 partials
__global__ __launch_bounds__(256) void k_moe(const unsigned short* __restrict__ h,
                                             const unsigned short* __restrict__ w2b,
                                             const int* __restrict__ counts,
                                             const int* __restrict__ offs,
                                             const int* __restrict__ rowsw,
                                             unsigned short* __restrict__ parts) {
    // grid 4096 = 8e x 2sp x 8nt x 32mt; mt innermost -> same-XCD share B-panel
    const int wg = (blockIdx.x & 7) * (gridDim.x >> 3) + (blockIdx.x >> 3);
    const int mt = wg & 31, nt = (wg >> 5) & 7, sp = (wg >> 8) & 1, e = wg >> 9;
    const int gn = counts[e];
    if (mt * 128 >= gn) return;
    const int gbase = offs[e];
    __shared__ __align__(16) short sA[128 * 64];
    __shared__ __align__(16) short sB[128 * 64];
    const int tid = threadIdx.x, lane = tid & 63, wid = tid >> 6;
    const int wm = wid >> 1, wn = wid & 1;
    const int srow = tid >> 3;
    const int cswz = ((tid & 7) ^ (srow & 7)) * 8;
    const unsigned short* pa[4];
    const unsigned short* pb[4];
#pragma unroll
    for (int c = 0; c < 4; ++c) {
        int lr = mt * 128 + 32 * c + srow;
        if (lr > gn - 1) lr = gn - 1;
        int grow = rowsw[gbase + lr] >> 1;
        pa[c] = h + (size_t)grow * HIDE + sp * KSPL + cswz;
        pb[c] = w2b + (size_t)(e * OUTE + nt * 128 + 32 * c + srow) * HIDE + sp * KSPL + cswz;
    }
    floatx4 acc[4][4] = {};
    core64(pa[0], pa[1], pa[2], pa[3], pb[0], pb[1], pb[2], pb[3],
           sA, sB, KSPL / 64, wm, wn, tid, lane, acc);
    unsigned short* pbase = parts + (size_t)sp * B_SZ * 2 * OUTE;
#pragma unroll
    for (int i = 0; i < 4; ++i)
#pragma unroll
        for (int j = 0; j < 4; ++j)
#pragma unroll
            for (int r = 0; r < 4; ++r) {
                int lr = mt * 128 + wm * 64 + i * 16 + (lane >> 4) * 4 + r;
                if (lr < gn) {
                    int at = gbase + lr;
                    int col = nt * 128 + wn * 64 + j * 16 + (lane & 15);
                    pbase[(size_t)at * OUTE + col] = f2bf(acc[i][j][r]);
                }
            }
}

// reduce: ymix[b] = sum_k tp[b,k] * (sum_sp parts[sp][slot(b,k)] + b2[e_k])
__global__ __launch_bounds__(256) void k_reduce(const unsigned short* __restrict__ parts,
                                                const int* __restrict__ slotof,
                                                const int* __restrict__ tidx,
                                                const float* __restrict__ tp,
                                                const float* __restrict__ b2,
                                                unsigned short* __restrict__ ymix) {
    int i = blockIdx.x * 256 + threadIdx.x;   // B_SZ * 256 threads, 4 cols each
    int b = i >> 8, col = (i & 255) * 4;
    int at0 = slotof[b * 2], at1 = slotof[b * 2 + 1];
    int e0 = tidx[b * 2], e1 = tidx[b * 2 + 1];
    float q0 = tp[b * 2], q1 = tp[b * 2 + 1];
    float y0[4] = {0.f, 0.f, 0.f, 0.f}, y1[4] = {0.f, 0.f, 0.f, 0.f};
#pragma unroll
    for (int sp = 0; sp < NSPLIT; ++sp) {
        ushort4 u0 = *(const ushort4*)(parts + ((size_t)sp * B_SZ * 2 + at0) * OUTE + col);
        ushort4 u1 = *(const ushort4*)(parts + ((size_t)sp * B_SZ * 2 + at1) * OUTE + col);
        y0[0] += bf2f(u0.x); y0[1] += bf2f(u0.y); y0[2] += bf2f(u0.z); y0[3] += bf2f(u0.w);
        y1[0] += bf2f(u1.x); y1[1] += bf2f(u1.y); y1[2] += bf2f(u1.z); y1[3] += bf2f(u1.w);
    }
    float4 bb0 = *(const float4*)(b2 + (size_t)e0 * OUTE + col);
    float4 bb1 = *(const float4*)(b2 + (size_t)e1 * OUTE + col);
    ushort4 o;
    o.x = f2bf(q0 * (y0[0] + bb0.x) + q1 * (y1[0] + bb1.x));
    o.y = f2bf(q0 * (y0[1] + bb0.y) + q1 * (y1[1] + bb1.y));
    o.z = f2bf(q0 * (y0[2] + bb0.z) + q1 * (y1[2] + bb1.z));
    o.w = f2bf(q0 * (y0[3] + bb0.w) + q1 * (y1[3] + bb1.w));
    *(ushort4*)(ymix + (size_t)b * OUTE + col) = o;
}

// ---------------- m97-style 128x128 BK32 core (small final GEMM, proven) -------
__device__ __forceinline__ void gemm_core(const unsigned short* sa0, const unsigned short* sa1,
                                          const unsigned short* sb0, const unsigned short* sb1,
                                          short* sA, short* sB, int nkt, int wid, int lane,
                                          floatx4 acc[4][4]) {
    short* ldsA0 = sA + (wid * 2 + 0) * 512;
    short* ldsA1 = sA + (wid * 2 + 1) * 512;
    short* ldsB0 = sB + (wid * 2 + 0) * 512;
    short* ldsB1 = sB + (wid * 2 + 1) * 512;
    const int wm = wid >> 1, wn = wid & 1;
    int aoff[4], boff[4];
#pragma unroll
    for (int i = 0; i < 4; ++i) {
        aoff[i] = (wm * 64 + i * 16 + (lane & 15)) * 32 + (lane >> 4) * 8;
        boff[i] = (wn * 64 + i * 16 + (lane & 15)) * 32 + (lane >> 4) * 8;
    }
    for (int kt = 0; kt < nkt; ++kt) {
        __syncthreads();
        async16(sa0, ldsA0);
        async16(sa1, ldsA1);
        async16(sb0, ldsB0);
        async16(sb1, ldsB1);
        sa0 += 32; sa1 += 32; sb0 += 32; sb1 += 32;
        __syncthreads();
        short8 av[4], bv[4];
#pragma unroll
        for (int i = 0; i < 4; ++i) av[i] = *(const short8*)(sA + aoff[i]);
#pragma unroll
        for (int j = 0; j < 4; ++j) bv[j] = *(const short8*)(sB + boff[j]);
#pragma unroll
        for (int i = 0; i < 4; ++i)
#pragma unroll
            for (int j = 0; j < 4; ++j)
                acc[i][j] = __builtin_amdgcn_mfma_f32_16x16x32_bf16(av[i], bv[j], acc[i][j], 0, 0, 0);
    }
}

// GEMM3: out = ymix @ Wc^T + bc
__global__ __launch_bounds__(256) void k_gemm_out(const unsigned short* __restrict__ ymix,
                                                  const unsigned short* __restrict__ wcb,
                                                  const float* __restrict__ bc,
                                                  float* __restrict__ out) {
    const int mt = blockIdx.x >> 3, nt = blockIdx.x & 7;
    const int m0 = mt * 128, n0 = nt * 128;
    __shared__ __align__(16) short sA[128 * 32];
    __shared__ __align__(16) short sB[128 * 32];
    const int lane = threadIdx.x & 63, wid = threadIdx.x >> 6;
    const int t0row = (wid * 2 + 0) * 16 + (lane >> 2);
    const int t1row = (wid * 2 + 1) * 16 + (lane >> 2);
    const int kb = (lane & 3) * 8;
    int br0 = n0 + t0row; if (br0 > NC - 1) br0 = NC - 1;
    int br1 = n0 + t1row; if (br1 > NC - 1) br1 = NC - 1;
    const unsigned short* sa0 = ymix + (size_t)(m0 + t0row) * IN_SZ + kb;
    const unsigned short* sa1 = ymix + (size_t)(m0 + t1row) * IN_SZ + kb;
    const unsigned short* sb0 = wcb + (size_t)br0 * IN_SZ + kb;
    const unsigned short* sb1 = wcb + (size_t)br1 * IN_SZ + kb;
    floatx4 acc[4][4] = {};
    gemm_core(sa0, sa1, sb0, sb1, sA, sB, IN_SZ / 32, wid, lane, acc);
    const int wm = wid >> 1, wn = wid & 1;
#pragma unroll
    for (int i = 0; i < 4; ++i)
#pragma unroll
        for (int j = 0; j < 4; ++j)
#pragma unroll
            for (int r = 0; r < 4; ++r) {
                int row = m0 + wm * 64 + i * 16 + (lane >> 4) * 4 + r;
                int col = n0 + wn * 64 + j * 16 + (lane & 15);
                if (col < NC)
                    out[(size_t)row * NC + col] = acc[i][j][r] + bc[col];
            }
}

extern "C" void kernel_launch(void* const* d_in, const int* in_sizes, int n_in,
                              void* d_out, int out_size, void* d_ws, size_t ws_size,
                              hipStream_t stream) {
    const float* x     = (const float*)d_in[0];
    const float* Wg    = (const float*)d_in[1];
    const float* bg    = (const float*)d_in[2];
    const float* gamma = (const float*)d_in[3];
    const float* beta  = (const float*)d_in[4];
    const float* W1    = (const float*)d_in[5];
    const float* b1    = (const float*)d_in[6];
    const float* W2    = (const float*)d_in[7];
    const float* b2    = (const float*)d_in[8];
    const float* Wc    = (const float*)d_in[9];
    const float* bc    = (const float*)d_in[10];
    float* out = (float*)d_out;

    char* ws = (char*)d_ws;
    size_t o = 0;
    auto carve = [&](size_t bytes) { char* p = ws + o; o += (bytes + 255) & ~(size_t)255; return p; };
    unsigned short* xb    = (unsigned short*)carve((size_t)B_SZ * IN_SZ * 2);
    unsigned short* w1b   = (unsigned short*)carve((size_t)HIDE * IN_SZ * 2);
    unsigned short* w2b   = (unsigned short*)carve((size_t)NE * OUTE * HIDE * 2);
    unsigned short* wcb   = (unsigned short*)carve((size_t)NC * IN_SZ * 2);
    unsigned short* h     = (unsigned short*)carve((size_t)B_SZ * HIDE * 2);
    unsigned short* parts = (unsigned short*)carve((size_t)NSPLIT * B_SZ * 2 * OUTE * 2);
    unsigned short* ymix  = (unsigned short*)carve((size_t)B_SZ * OUTE * 2);
    float* logits = (float*)carve((size_t)B_SZ * NE * 4);
    float* Gx     = (float*)carve((size_t)B_SZ * 4);
    int*   tidx   = (int*)carve((size_t)B_SZ * 2 * 4);
    float* tp     = (float*)carve((size_t)B_SZ * 2 * 4);
    int*   rowsw  = (int*)carve((size_t)B_SZ * 2 * 4);
    int*   slotof = (int*)carve((size_t)B_SZ * 2 * 4);
    int*   ctrl   = (int*)carve(256);
    int* counts  = ctrl;
    int* cursors = ctrl + 8;
    int* offs    = ctrl + 16;
    float* gsum  = (float*)(ctrl + 24);

    k_cvt<<<2048, 256, 0, stream>>>(x,  xb,  B_SZ * IN_SZ);
    k_cvt<<<2048, 256, 0, stream>>>(W1, w1b, HIDE * IN_SZ);
    k_cvt<<<2048, 256, 0, stream>>>(W2, w2b, NE * OUTE * HIDE);
    k_cvt<<<2048, 256, 0, stream>>>(Wc, wcb, NC * IN_SZ);

    k_gate<<<B_SZ / 4, 256, 0, stream>>>(x, Wg, bg, logits, Gx);
    k_gsum<<<1, 1024, 0, stream>>>(Gx, gsum);
    k_zeroctrl<<<1, 64, 0, stream>>>(ctrl);
    k_topk<<<B_SZ / 256, 256, 0, stream>>>(logits, Gx, gsum, gamma, beta, tidx, tp, counts);
    k_offsets<<<1, 64, 0, stream>>>(counts, offs);
    k_fill<<<B_SZ / 256, 256, 0, stream>>>(tidx, tp, offs, cursors, rowsw, slotof);

    k_h8<<<(B_SZ / 128) * (HIDE / 128), 256, 0, stream>>>(xb, w1b, b1, h);
    k_moe<<<NE * 32 * 8 * NSPLIT, 256, 0, stream>>>(h, w2b, counts, offs, rowsw, parts);
    k_reduce<<<B_SZ, 256, 0, stream>>>(parts, slotof, tidx, tp, b2, ymix);
    k_gemm_out<<<(B_SZ / 128) * 8, 256, 0, stream>>>(ymix, wcb, bc, out);
}

// Round 6
// 922.405 us; speedup vs baseline: 1.9181x; 1.1528x over previous
//
#include <hip/hip_runtime.h>
#include <stdint.h>

#define B_SZ   4096
#define IN_SZ  1024
#define NE     8
#define NC     1000
#define HIDE   16384   // HID*E
#define OUTE   1024    // OUT per expert
#define GEPS   1e-6f
#define NSPLIT 2
#define KSPL   8192    // HIDE / NSPLIT

typedef __attribute__((ext_vector_type(8))) short short8;
typedef __attribute__((ext_vector_type(4))) float floatx4;

__device__ __forceinline__ unsigned short f2bf(float f) {
    unsigned u = __float_as_uint(f);
    u += 0x7fffu + ((u >> 16) & 1u);
    return (unsigned short)(u >> 16);
}
__device__ __forceinline__ float bf2f(unsigned short h) {
    return __uint_as_float(((unsigned)h) << 16);
}

__device__ __forceinline__ void async16(const void* g, void* l) {
    __builtin_amdgcn_global_load_lds(
        (const __attribute__((address_space(1))) void*)g,
        (__attribute__((address_space(3))) void*)l, 16, 0, 0);
}

// ---------------- conversion fp32 -> bf16 ---------------------------------------
__global__ __launch_bounds__(256) void k_cvt(const float* __restrict__ src,
                                             unsigned short* __restrict__ dst, int n) {
    int i = (blockIdx.x * 256 + threadIdx.x) * 4;
    int stride = gridDim.x * 256 * 4;
    for (; i < n; i += stride) {
        float4 v = *(const float4*)(src + i);
        ushort4 o;
        o.x = f2bf(v.x); o.y = f2bf(v.y); o.z = f2bf(v.z); o.w = f2bf(v.w);
        *(ushort4*)(dst + i) = o;
    }
}

// ---------------- gating (fp32 exact) -------------------------------------------
__global__ __launch_bounds__(256) void k_gate(const float* __restrict__ x,
                                              const float* __restrict__ Wg,
                                              const float* __restrict__ bg,
                                              float* __restrict__ logits,
                                              float* __restrict__ Gx) {
    int wid = threadIdx.x >> 6, lane = threadIdx.x & 63;
    int b = blockIdx.x * 4 + wid;
    const float* xr = x + (size_t)b * IN_SZ;
    float xv[16];
#pragma unroll
    for (int t = 0; t < 16; ++t) xv[t] = xr[lane + 64 * t];
    float lg[NE];
#pragma unroll
    for (int e = 0; e < NE; ++e) {
        const float* wr = Wg + e * IN_SZ;
        float s = 0.f;
#pragma unroll
        for (int t = 0; t < 16; ++t) s += xv[t] * wr[lane + 64 * t];
#pragma unroll
        for (int m = 32; m >= 1; m >>= 1) s += __shfl_xor(s, m, 64);
        lg[e] = s + bg[e];
    }
    if (lane == 0) {
        float ss = 0.f;
#pragma unroll
        for (int e = 0; e < NE; ++e) { logits[b * NE + e] = lg[e]; ss += lg[e] * lg[e]; }
        Gx[b] = sqrtf(ss);
    }
}

__global__ __launch_bounds__(1024) void k_gsum(const float* __restrict__ Gx, float* __restrict__ gsum) {
    __shared__ float sm[1024];
    int t = threadIdx.x;
    sm[t] = Gx[t] + Gx[t + 1024] + Gx[t + 2048] + Gx[t + 3072];
    __syncthreads();
    for (int m = 512; m >= 1; m >>= 1) {
        if (t < m) sm[t] += sm[t + m];
        __syncthreads();
    }
    if (t == 0) gsum[0] = sm[0];
}

__global__ void k_zeroctrl(int* ctrl) {
    if (threadIdx.x < 24) ctrl[threadIdx.x] = 0;
}

__global__ __launch_bounds__(256) void k_topk(const float* __restrict__ logits,
                                              const float* __restrict__ Gx,
                                              const float* __restrict__ gsum,
                                              const float* __restrict__ gamma,
                                              const float* __restrict__ beta,
                                              int* __restrict__ tidx, float* __restrict__ tp,
                                              int* __restrict__ counts) {
    int b = blockIdx.x * 256 + threadIdx.x;
    float nx = Gx[b] / (gsum[0] * (1.0f / (float)B_SZ) + GEPS);
    float l[NE];
    float mx = -1e30f;
#pragma unroll
    for (int e = 0; e < NE; ++e) {
        l[e] = gamma[e] * (logits[b * NE + e] * nx) + beta[e];
        mx = fmaxf(mx, l[e]);
    }
    float se = 0.f;
#pragma unroll
    for (int e = 0; e < NE; ++e) { l[e] = expf(l[e] - mx); se += l[e]; }
    float inv = 1.f / se;
    int i0 = 0; float p0 = l[0];
#pragma unroll
    for (int e = 1; e < NE; ++e) if (l[e] > p0) { p0 = l[e]; i0 = e; }
    int i1 = -1; float p1 = -1.f;
#pragma unroll
    for (int e = 0; e < NE; ++e) if (e != i0 && l[e] > p1) { p1 = l[e]; i1 = e; }
    tidx[b * 2 + 0] = i0; tidx[b * 2 + 1] = i1;
    tp[b * 2 + 0] = p0 * inv; tp[b * 2 + 1] = p1 * inv;
    atomicAdd(&counts[i0], 1);
    atomicAdd(&counts[i1], 1);
}

__global__ void k_offsets(const int* __restrict__ counts, int* __restrict__ offs) {
    if (threadIdx.x == 0) {
        int a = 0;
        for (int e = 0; e < NE; ++e) { offs[e] = a; a += counts[e]; }
    }
}

__global__ __launch_bounds__(256) void k_fill(const int* __restrict__ tidx, const float* __restrict__ tp,
                                              const int* __restrict__ offs, int* __restrict__ cursors,
                                              int* __restrict__ rowsw, int* __restrict__ slotof) {
    int b = blockIdx.x * 256 + threadIdx.x;
#pragma unroll
    for (int k = 0; k < 2; ++k) {
        int e = tidx[b * 2 + k];
        int pos = atomicAdd(&cursors[e], 1);
        int at = offs[e] + pos;
        rowsw[at] = b * 2 + k;
        slotof[b * 2 + k] = at;
    }
}

// ====== 128x128 / BK=64, XOR-swizzled (0-conflict, round-5 verified), now ======
// ====== DOUBLE-BUFFERED minimum-2-phase pipeline (T3 catalog recipe)      ======
// LDS: buf{0,1} x (A 16KB | B 16KB) = 64KB. LDS[r][slot] holds global chunk
// slot^(r&7); pre-swizzled global source + swizzled ds_read (both-sides).
// Per K-step: STAGE(buf^1, t+1) issued FIRST, then ds_read buf[cur] ->
// lgkmcnt(0) -> MFMA cluster (setprio) -> __syncthreads (drains the prefetch
// vmcnt + orders the flip). Stage latency hides under 32 MFMAs + 2 blocks/CU.

__device__ __forceinline__ void stage_bk64(const unsigned short* const* pa,
                                           const unsigned short* const* pb,
                                           char* bufc, int koff, int tid) {
#pragma unroll
    for (int c = 0; c < 4; ++c) {
        async16(pa[c] + koff, bufc + c * 4096 + tid * 16);
        async16(pb[c] + koff, bufc + 16384 + c * 4096 + tid * 16);
    }
}

__device__ __forceinline__ void compute_bk64(const short* buf, const int* aoff, const int* boff,
                                             floatx4 acc[4][4]) {
    const short* sA = buf;
    const short* sB = buf + 8192;
    short8 a0[4], a1[4], b0[4], b1[4];
#pragma unroll
    for (int i = 0; i < 4; ++i) {
        a0[i] = *(const short8*)(sA + aoff[i]);
        a1[i] = *(const short8*)(sA + (aoff[i] ^ 32));
        b0[i] = *(const short8*)(sB + boff[i]);
        b1[i] = *(const short8*)(sB + (boff[i] ^ 32));
    }
    asm volatile("s_waitcnt lgkmcnt(0)" ::: "memory");
    __builtin_amdgcn_sched_barrier(0);
    __builtin_amdgcn_s_setprio(1);
#pragma unroll
    for (int i = 0; i < 4; ++i)
#pragma unroll
        for (int j = 0; j < 4; ++j) {
            acc[i][j] = __builtin_amdgcn_mfma_f32_16x16x32_bf16(a0[i], b0[j], acc[i][j], 0, 0, 0);
            acc[i][j] = __builtin_amdgcn_mfma_f32_16x16x32_bf16(a1[i], b1[j], acc[i][j], 0, 0, 0);
        }
    __builtin_amdgcn_s_setprio(0);
}

// nkt must be even. smem = 65536B dynamic.
__device__ __forceinline__ void core64db(const unsigned short* const* pa,
                                         const unsigned short* const* pb,
                                         short* smem, int nkt, int wm, int wn,
                                         int tid, int lane, floatx4 acc[4][4]) {
    char* b0c = (char*)smem;
    char* b1c = b0c + 32768;
    const int sl = ((lane >> 4) ^ (lane & 7)) * 8;
    int aoff[4], boff[4];
#pragma unroll
    for (int i = 0; i < 4; ++i) {
        aoff[i] = (wm * 64 + i * 16 + (lane & 15)) * 64 + sl;
        boff[i] = (wn * 64 + i * 16 + (lane & 15)) * 64 + sl;
    }
    stage_bk64(pa, pb, b0c, 0, tid);
    __syncthreads();
#pragma unroll 1
    for (int kt = 0; kt < nkt; kt += 2) {
        if (kt + 1 < nkt) stage_bk64(pa, pb, b1c, (kt + 1) * 64, tid);
        compute_bk64(smem, aoff, boff, acc);
        __syncthreads();
        if (kt + 2 < nkt) stage_bk64(pa, pb, b0c, (kt + 2) * 64, tid);
        compute_bk64(smem + 16384, aoff, boff, acc);
        __syncthreads();
    }
}

// GEMM1: h = relu(x @ W1^T + b1)  [4096,1024] x [16384,1024]^T -> bf16 [4096,16384]
__global__ __launch_bounds__(256) void k_h8(const unsigned short* __restrict__ xb,
                                            const unsigned short* __restrict__ w1b,
                                            const float* __restrict__ b1,
                                            unsigned short* __restrict__ hout) {
    extern __shared__ short smem[];
    const int tid = threadIdx.x, lane = tid & 63, wid = tid >> 6;
    const int wm = wid >> 1, wn = wid & 1;
    const int wg = (blockIdx.x & 7) * (gridDim.x >> 3) + (blockIdx.x >> 3);
    const int mt = wg & 31, nt = wg >> 5;
    const int m0 = mt * 128, n0 = nt * 128;
    const int srow = tid >> 3;
    const int cswz = ((tid & 7) ^ (srow & 7)) * 8;
    const unsigned short* pa[4];
    const unsigned short* pb[4];
#pragma unroll
    for (int c = 0; c < 4; ++c) {
        pa[c] = xb  + (size_t)(m0 + 32 * c + srow) * IN_SZ + cswz;
        pb[c] = w1b + (size_t)(n0 + 32 * c + srow) * IN_SZ + cswz;
    }
    floatx4 acc[4][4] = {};
    core64db(pa, pb, smem, IN_SZ / 64, wm, wn, tid, lane, acc);
#pragma unroll
    for (int i = 0; i < 4; ++i)
#pragma unroll
        for (int j = 0; j < 4; ++j)
#pragma unroll
            for (int r = 0; r < 4; ++r) {
                int row = m0 + wm * 64 + i * 16 + (lane >> 4) * 4 + r;
                int col = n0 + wn * 64 + j * 16 + (lane & 15);
                float v = acc[i][j][r] + b1[col];
                hout[(size_t)row * HIDE + col] = f2bf(fmaxf(v, 0.f));
            }
}

// GEMM2 grouped, split-K=2: gathered h rows x W2 expert slice -> bf16 partials
__global__ __launch_bounds__(256) void k_moe(const unsigned short* __restrict__ h,
                                             const unsigned short* __restrict__ w2b,
                                             const int* __restrict__ counts,
                                             const int* __restrict__ offs,
                                             const int* __restrict__ rowsw,
                                             unsigned short* __restrict__ parts) {
    // grid 4096 = 8e x 2sp x 8nt x 32mt; mt innermost -> same-XCD share B-panel
    const int wg = (blockIdx.x & 7) * (gridDim.x >> 3) + (blockIdx.x >> 3);
    const int mt = wg & 31, nt = (wg >> 5) & 7, sp = (wg >> 8) & 1, e = wg >> 9;
    const int gn = counts[e];
    if (mt * 128 >= gn) return;
    const int gbase = offs[e];
    extern __shared__ short smem[];
    const int tid = threadIdx.x, lane = tid & 63, wid = tid >> 6;
    const int wm = wid >> 1, wn = wid & 1;
    const int srow = tid >> 3;
    const int cswz = ((tid & 7) ^ (srow & 7)) * 8;
    const unsigned short* pa[4];
    const unsigned short* pb[4];
#pragma unroll
    for (int c = 0; c < 4; ++c) {
        int lr = mt * 128 + 32 * c + srow;
        if (lr > gn - 1) lr = gn - 1;
        int grow = rowsw[gbase + lr] >> 1;
        pa[c] = h + (size_t)grow * HIDE + sp * KSPL + cswz;
        pb[c] = w2b + (size_t)(e * OUTE + nt * 128 + 32 * c + srow) * HIDE + sp * KSPL + cswz;
    }
    floatx4 acc[4][4] = {};
    core64db(pa, pb, smem, KSPL / 64, wm, wn, tid, lane, acc);
    unsigned short* pbase = parts + (size_t)sp * B_SZ * 2 * OUTE;
#pragma unroll
    for (int i = 0; i < 4; ++i)
#pragma unroll
        for (int j = 0; j < 4; ++j)
#pragma unroll
            for (int r = 0; r < 4; ++r) {
                int lr = mt * 128 + wm * 64 + i * 16 + (lane >> 4) * 4 + r;
                if (lr < gn) {
                    int at = gbase + lr;
                    int col = nt * 128 + wn * 64 + j * 16 + (lane & 15);
                    pbase[(size_t)at * OUTE + col] = f2bf(acc[i][j][r]);
                }
            }
}

// reduce: ymix[b] = sum_k tp[b,k] * (sum_sp parts[sp][slot(b,k)] + b2[e_k])
__global__ __launch_bounds__(256) void k_reduce(const unsigned short* __restrict__ parts,
                                                const int* __restrict__ slotof,
                                                const int* __restrict__ tidx,
                                                const float* __restrict__ tp,
                                                const float* __restrict__ b2,
                                                unsigned short* __restrict__ ymix) {
    int i = blockIdx.x * 256 + threadIdx.x;   // B_SZ * 256 threads, 4 cols each
    int b = i >> 8, col = (i & 255) * 4;
    int at0 = slotof[b * 2], at1 = slotof[b * 2 + 1];
    int e0 = tidx[b * 2], e1 = tidx[b * 2 + 1];
    float q0 = tp[b * 2], q1 = tp[b * 2 + 1];
    float y0[4] = {0.f, 0.f, 0.f, 0.f}, y1[4] = {0.f, 0.f, 0.f, 0.f};
#pragma unroll
    for (int sp = 0; sp < NSPLIT; ++sp) {
        ushort4 u0 = *(const ushort4*)(parts + ((size_t)sp * B_SZ * 2 + at0) * OUTE + col);
        ushort4 u1 = *(const ushort4*)(parts + ((size_t)sp * B_SZ * 2 + at1) * OUTE + col);
        y0[0] += bf2f(u0.x); y0[1] += bf2f(u0.y); y0[2] += bf2f(u0.z); y0[3] += bf2f(u0.w);
        y1[0] += bf2f(u1.x); y1[1] += bf2f(u1.y); y1[2] += bf2f(u1.z); y1[3] += bf2f(u1.w);
    }
    float4 bb0 = *(const float4*)(b2 + (size_t)e0 * OUTE + col);
    float4 bb1 = *(const float4*)(b2 + (size_t)e1 * OUTE + col);
    ushort4 o;
    o.x = f2bf(q0 * (y0[0] + bb0.x) + q1 * (y1[0] + bb1.x));
    o.y = f2bf(q0 * (y0[1] + bb0.y) + q1 * (y1[1] + bb1.y));
    o.z = f2bf(q0 * (y0[2] + bb0.z) + q1 * (y1[2] + bb1.z));
    o.w = f2bf(q0 * (y0[3] + bb0.w) + q1 * (y1[3] + bb1.w));
    *(ushort4*)(ymix + (size_t)b * OUTE + col) = o;
}

// GEMM3: out = ymix @ Wc^T + bc  (same dbuf core, B rows clamped to NC)
__global__ __launch_bounds__(256) void k_gemm_out(const unsigned short* __restrict__ ymix,
                                                  const unsigned short* __restrict__ wcb,
                                                  const float* __restrict__ bc,
                                                  float* __restrict__ out) {
    const int mt = blockIdx.x >> 3, nt = blockIdx.x & 7;
    const int m0 = mt * 128, n0 = nt * 128;
    extern __shared__ short smem[];
    const int tid = threadIdx.x, lane = tid & 63, wid = tid >> 6;
    const int wm = wid >> 1, wn = wid & 1;
    const int srow = tid >> 3;
    const int cswz = ((tid & 7) ^ (srow & 7)) * 8;
    const unsigned short* pa[4];
    const unsigned short* pb[4];
#pragma unroll
    for (int c = 0; c < 4; ++c) {
        pa[c] = ymix + (size_t)(m0 + 32 * c + srow) * IN_SZ + cswz;
        int br = n0 + 32 * c + srow; if (br > NC - 1) br = NC - 1;
        pb[c] = wcb + (size_t)br * IN_SZ + cswz;
    }
    floatx4 acc[4][4] = {};
    core64db(pa, pb, smem, IN_SZ / 64, wm, wn, tid, lane, acc);
#pragma unroll
    for (int i = 0; i < 4; ++i)
#pragma unroll
        for (int j = 0; j < 4; ++j)
#pragma unroll
            for (int r = 0; r < 4; ++r) {
                int row = m0 + wm * 64 + i * 16 + (lane >> 4) * 4 + r;
                int col = n0 + wn * 64 + j * 16 + (lane & 15);
                if (col < NC)
                    out[(size_t)row * NC + col] = acc[i][j][r] + bc[col];
            }
}

extern "C" void kernel_launch(void* const* d_in, const int* in_sizes, int n_in,
                              void* d_out, int out_size, void* d_ws, size_t ws_size,
                              hipStream_t stream) {
    const float* x     = (const float*)d_in[0];
    const float* Wg    = (const float*)d_in[1];
    const float* bg    = (const float*)d_in[2];
    const float* gamma = (const float*)d_in[3];
    const float* beta  = (const float*)d_in[4];
    const float* W1    = (const float*)d_in[5];
    const float* b1    = (const float*)d_in[6];
    const float* W2    = (const float*)d_in[7];
    const float* b2    = (const float*)d_in[8];
    const float* Wc    = (const float*)d_in[9];
    const float* bc    = (const float*)d_in[10];
    float* out = (float*)d_out;

    char* ws = (char*)d_ws;
    size_t o = 0;
    auto carve = [&](size_t bytes) { char* p = ws + o; o += (bytes + 255) & ~(size_t)255; return p; };
    unsigned short* xb    = (unsigned short*)carve((size_t)B_SZ * IN_SZ * 2);
    unsigned short* w1b   = (unsigned short*)carve((size_t)HIDE * IN_SZ * 2);
    unsigned short* w2b   = (unsigned short*)carve((size_t)NE * OUTE * HIDE * 2);
    unsigned short* wcb   = (unsigned short*)carve((size_t)NC * IN_SZ * 2);
    unsigned short* h     = (unsigned short*)carve((size_t)B_SZ * HIDE * 2);
    unsigned short* parts = (unsigned short*)carve((size_t)NSPLIT * B_SZ * 2 * OUTE * 2);
    unsigned short* ymix  = (unsigned short*)carve((size_t)B_SZ * OUTE * 2);
    float* logits = (float*)carve((size_t)B_SZ * NE * 4);
    float* Gx     = (float*)carve((size_t)B_SZ * 4);
    int*   tidx   = (int*)carve((size_t)B_SZ * 2 * 4);
    float* tp     = (float*)carve((size_t)B_SZ * 2 * 4);
    int*   rowsw  = (int*)carve((size_t)B_SZ * 2 * 4);
    int*   slotof = (int*)carve((size_t)B_SZ * 2 * 4);
    int*   ctrl   = (int*)carve(256);
    int* counts  = ctrl;
    int* cursors = ctrl + 8;
    int* offs    = ctrl + 16;
    float* gsum  = (float*)(ctrl + 24);

    // 64KB dynamic LDS for the dbuf GEMM kernels (idempotent, not captured)
    hipFuncSetAttribute((const void*)k_h8,       hipFuncAttributeMaxDynamicSharedMemorySize, 65536);
    hipFuncSetAttribute((const void*)k_moe,      hipFuncAttributeMaxDynamicSharedMemorySize, 65536);
    hipFuncSetAttribute((const void*)k_gemm_out, hipFuncAttributeMaxDynamicSharedMemorySize, 65536);

    k_cvt<<<2048, 256, 0, stream>>>(x,  xb,  B_SZ * IN_SZ);
    k_cvt<<<2048, 256, 0, stream>>>(W1, w1b, HIDE * IN_SZ);
    k_cvt<<<2048, 256, 0, stream>>>(W2, w2b, NE * OUTE * HIDE);
    k_cvt<<<2048, 256, 0, stream>>>(Wc, wcb, NC * IN_SZ);

    k_gate<<<B_SZ / 4, 256, 0, stream>>>(x, Wg, bg, logits, Gx);
    k_gsum<<<1, 1024, 0, stream>>>(Gx, gsum);
    k_zeroctrl<<<1, 64, 0, stream>>>(ctrl);
    k_topk<<<B_SZ / 256, 256, 0, stream>>>(logits, Gx, gsum, gamma, beta, tidx, tp, counts);
    k_offsets<<<1, 64, 0, stream>>>(counts, offs);
    k_fill<<<B_SZ / 256, 256, 0, stream>>>(tidx, tp, offs, cursors, rowsw, slotof);

    k_h8<<<(B_SZ / 128) * (HIDE / 128), 256, 65536, stream>>>(xb, w1b, b1, h);
    k_moe<<<NE * 32 * 8 * NSPLIT, 256, 65536, stream>>>(h, w2b, counts, offs, rowsw, parts);
    k_reduce<<<B_SZ, 256, 0, stream>>>(parts, slotof, tidx, tp, b2, ymix);
    k_gemm_out<<<(B_SZ / 128) * 8, 256, 65536, stream>>>(ymix, wcb, bc, out);
}